// Round 3
// baseline (368.352 us; speedup 1.0000x reference)
//
#include <hip/hip_runtime.h>

// SliceNApply: bilateral-grid trilinear slice + per-pixel 3x4 affine apply.
// FP32 tensors. B=4, C=12, D=8, Hg=Wg=16, H=W=1024.
//
// R3: (1) LDS holds z-pairs (g[s],g[s+1]) packed as bf16x2 in one dword ->
//     12 ds_read_b128 per pixel instead of 24 (lossless: inputs are
//     bf16-rounded, evidenced by absmax == 1 bf16-ulp in R2).
// (2) wave = tile quadrant -> by/bx wave-uniform; LDS addresses within one
//     b128 differ only in z-slot. ZSTRIDE=132 (=4 mod 32) puts slot s on
//     bank group 4s -> 8 slots tile all 32 banks, broadcast handles aliases.
// (3) launch_bounds(256,4): 4 blocks/CU -> full 1024-block grid resident.

#define ZSTRIDE 132   // 9 cells * 12 ch = 108 dwords + 24 pad (132 % 32 == 4)

static __device__ __forceinline__ unsigned short f2bf(float f) {
    // round-to-nearest-even f32 -> bf16 (finite inputs)
    unsigned int u = __float_as_uint(f);
    u += ((u >> 16) & 1u) + 0x7FFFu;
    return (unsigned short)(u >> 16);
}
static __device__ __forceinline__ float bf_lo(unsigned int d) {
    return __uint_as_float(d << 16);
}
static __device__ __forceinline__ float bf_hi(unsigned int d) {
    return __uint_as_float(d & 0xFFFF0000u);
}

__global__ __launch_bounds__(256, 4) void slice_apply(
    const float* __restrict__ grid,   // [4][12][8][16][16]
    const float* __restrict__ guide,  // [4][1][1024][1024]
    const float* __restrict__ fr,     // [4][3][1024][1024]
    float* __restrict__ out)          // [4][3][1024][1024]
{
    __shared__ unsigned int lds[8 * ZSTRIDE];

    const int b     = blockIdx.y;
    const int tileX = blockIdx.x & 15;
    const int tileY = blockIdx.x >> 4;
    const int t     = threadIdx.x;

    int px[3], py[3];
#pragma unroll
    for (int j = 0; j < 3; ++j) {
        px[j] = min(max(tileX - 1 + j, 0), 15);
        py[j] = min(max(tileY - 1 + j, 0), 15);
    }

    // ---- stage grid slice into LDS, z-pair packed as bf16x2 ----
    for (int e = t; e < 8 * 9 * 12; e += 256) {
        const int c    = e % 12;
        const int cell = (e / 12) % 9;
        const int s    = e / 108;
        const int s2   = min(s + 1, 7);
        const int cb   = (b * 12 + c) * 8;
        const int sp   = py[cell / 3] * 16 + px[cell % 3];
        const float lo = grid[(cb + s)  * 256 + sp];
        const float hi = grid[(cb + s2) * 256 + sp];
        lds[s * ZSTRIDE + cell * 12 + c] =
            (unsigned int)f2bf(lo) | ((unsigned int)f2bf(hi) << 16);
    }
    __syncthreads();

    // wave = quadrant (32x32 px): by/bx wave-uniform
    const int w  = t >> 6;
    const int l  = t & 63;
    const int by = w >> 1;
    const int bx = w & 1;
    const int lx = bx * 32 + (l & 7) * 4;  // local x of 4-px strip
    const int rr = l >> 3;                 // row within 8-row stripe

    // loop-invariant per-pixel x weights
    float u0[4], u1[4];
#pragma unroll
    for (int p = 0; p < 4; ++p) {
        const float wx = ((float)(lx + p) + 0.5f) * 0.015625f + (0.5f - (float)bx);
        u1[p] = wx;
        u0[p] = 1.0f - wx;
    }

    // wave-uniform corner dword offsets
    int cofs[4];
#pragma unroll
    for (int k = 0; k < 4; ++k) {
        const int dy = k >> 1, dx = k & 1;
        cofs[k] = ((by + dy) * 3 + (bx + dx)) * 12;
    }

#pragma unroll
    for (int it = 0; it < 4; ++it) {
        const int ly = by * 32 + it * 8 + rr;   // tile-local y
        const int y  = tileY * 64 + ly;
        const float wy = ((float)ly + 0.5f) * 0.015625f + (0.5f - (float)by);
        const float v1 = wy, v0 = 1.0f - wy;

        const int gofs = (b * 1024 + y) * 1024 + tileX * 64 + lx;
        const int fofs = ((b * 3) * 1024 + y) * 1024 + tileX * 64 + lx;

        const float4 gv  = *reinterpret_cast<const float4*>(guide + gofs);
        const float4 f0v = *reinterpret_cast<const float4*>(fr + fofs);
        const float4 f1v = *reinterpret_cast<const float4*>(fr + fofs + 1048576);
        const float4 f2v = *reinterpret_cast<const float4*>(fr + fofs + 2097152);

        const float gva[4] = {gv.x, gv.y, gv.z, gv.w};
        const float fa0[4] = {f0v.x, f0v.y, f0v.z, f0v.w};
        const float fa1[4] = {f1v.x, f1v.y, f1v.z, f1v.w};
        const float fa2[4] = {f2v.x, f2v.y, f2v.z, f2v.w};

        float o0a[4], o1a[4], o2a[4];

#pragma unroll
        for (int p = 0; p < 4; ++p) {
            const float g  = gva[p];
            const float gz = g * 8.0f - 0.5f;
            int s = (int)floorf(gz);
            s = min(max(s, 0), 7);
            const float wz = fmaxf(gz - (float)s, 0.0f);
            const float zl = 1.0f - wz, zh = wz;
            const int sbase = s * ZSTRIDE;

            float acc[12];
#pragma unroll
            for (int c = 0; c < 12; ++c) acc[c] = 0.0f;

#pragma unroll
            for (int k = 0; k < 4; ++k) {
                const float wgt = ((k >> 1) ? v1 : v0) * ((k & 1) ? u1[p] : u0[p]);
                const float wl = wgt * zl;
                const float wh = wgt * zh;
                const unsigned int* cp = &lds[sbase + cofs[k]];
#pragma unroll
                for (int q = 0; q < 3; ++q) {
                    const uint4 dq = *reinterpret_cast<const uint4*>(cp + q * 4);
                    const unsigned int dw[4] = {dq.x, dq.y, dq.z, dq.w};
#pragma unroll
                    for (int kk = 0; kk < 4; ++kk) {
                        const int c = q * 4 + kk;
                        acc[c] = fmaf(wl, bf_lo(dw[kk]), acc[c]);
                        acc[c] = fmaf(wh, bf_hi(dw[kk]), acc[c]);
                    }
                }
            }

            const float f0 = fa0[p], f1 = fa1[p], f2 = fa2[p];
            o0a[p] = fmaf(acc[0], f0, fmaf(acc[1], f1, fmaf(acc[2],  f2, acc[3])));
            o1a[p] = fmaf(acc[4], f0, fmaf(acc[5], f1, fmaf(acc[6],  f2, acc[7])));
            o2a[p] = fmaf(acc[8], f0, fmaf(acc[9], f1, fmaf(acc[10], f2, acc[11])));
        }

        const float4 O0 = {o0a[0], o0a[1], o0a[2], o0a[3]};
        const float4 O1 = {o1a[0], o1a[1], o1a[2], o1a[3]};
        const float4 O2 = {o2a[0], o2a[1], o2a[2], o2a[3]};
        *reinterpret_cast<float4*>(out + fofs)           = O0;
        *reinterpret_cast<float4*>(out + fofs + 1048576) = O1;
        *reinterpret_cast<float4*>(out + fofs + 2097152) = O2;
    }
}

extern "C" void kernel_launch(void* const* d_in, const int* in_sizes, int n_in,
                              void* d_out, int out_size, void* d_ws, size_t ws_size,
                              hipStream_t stream) {
    const float* grid  = (const float*)d_in[0];
    const float* guide = (const float*)d_in[1];
    const float* fr    = (const float*)d_in[2];
    float* out = (float*)d_out;

    dim3 g(256, 4);   // 16x16 tiles of 64x64 px, 4 batches
    dim3 blk(256);
    hipLaunchKernelGGL(slice_apply, g, blk, 0, stream, grid, guide, fr, out);
}

// Round 4
// 268.694 us; speedup vs baseline: 1.3709x; 1.3709x over previous
//
#include <hip/hip_runtime.h>

// SliceNApply: bilateral-grid trilinear slice + per-pixel 3x4 affine apply.
// FP32 tensors. B=4, C=12, D=8, Hg=Wg=16, H=W=1024.
//
// R4 = R3 structure with the occupancy knob reverted:
//  - __launch_bounds__(256,3): R3's (256,4) made the compiler chase the
//    8-waves/EU tier (VGPR 64 = 512/8) and spill ~3.3KB/thread to scratch
//    -> hbm_bytes 973 MB, 283 us. (256,3) was R2-proven spill-free.
//  - LDS z-pair packing (g[s],g[s+1]) as bf16x2: 12 ds_read_b128/px.
//  - wave = tile quadrant -> bx/by wave-uniform; ZSTRIDE=132 (=4 mod 32):
//    z-slot s -> bank group 4s, 8 slots tile 32 banks. Measured ~0 conflicts.

#define ZSTRIDE 132   // 9 cells * 12 ch = 108 dwords + 24 pad

static __device__ __forceinline__ unsigned short f2bf(float f) {
    unsigned int u = __float_as_uint(f);
    u += ((u >> 16) & 1u) + 0x7FFFu;
    return (unsigned short)(u >> 16);
}
static __device__ __forceinline__ float bf_lo(unsigned int d) {
    return __uint_as_float(d << 16);
}
static __device__ __forceinline__ float bf_hi(unsigned int d) {
    return __uint_as_float(d & 0xFFFF0000u);
}

__global__ __launch_bounds__(256, 3) void slice_apply(
    const float* __restrict__ grid,   // [4][12][8][16][16]
    const float* __restrict__ guide,  // [4][1][1024][1024]
    const float* __restrict__ fr,     // [4][3][1024][1024]
    float* __restrict__ out)          // [4][3][1024][1024]
{
    __shared__ unsigned int lds[8 * ZSTRIDE];

    const int b     = blockIdx.y;
    const int tileX = blockIdx.x & 15;
    const int tileY = blockIdx.x >> 4;
    const int t     = threadIdx.x;

    int px[3], py[3];
#pragma unroll
    for (int j = 0; j < 3; ++j) {
        px[j] = min(max(tileX - 1 + j, 0), 15);
        py[j] = min(max(tileY - 1 + j, 0), 15);
    }

    // ---- stage grid slice into LDS, z-pair packed as bf16x2 ----
    for (int e = t; e < 8 * 9 * 12; e += 256) {
        const int c    = e % 12;
        const int cell = (e / 12) % 9;
        const int s    = e / 108;
        const int s2   = min(s + 1, 7);
        const int cb   = (b * 12 + c) * 8;
        const int sp   = py[cell / 3] * 16 + px[cell % 3];
        const float lo = grid[(cb + s)  * 256 + sp];
        const float hi = grid[(cb + s2) * 256 + sp];
        lds[s * ZSTRIDE + cell * 12 + c] =
            (unsigned int)f2bf(lo) | ((unsigned int)f2bf(hi) << 16);
    }
    __syncthreads();

    // wave = quadrant (32x32 px): by/bx wave-uniform
    const int w  = t >> 6;
    const int l  = t & 63;
    const int by = w >> 1;
    const int bx = w & 1;
    const int lx = bx * 32 + (l & 7) * 4;  // local x of 4-px strip
    const int rr = l >> 3;                 // row within 8-row stripe

    float u0[4], u1[4];
#pragma unroll
    for (int p = 0; p < 4; ++p) {
        const float wx = ((float)(lx + p) + 0.5f) * 0.015625f + (0.5f - (float)bx);
        u1[p] = wx;
        u0[p] = 1.0f - wx;
    }

    int cofs[4];
#pragma unroll
    for (int k = 0; k < 4; ++k) {
        const int dy = k >> 1, dx = k & 1;
        cofs[k] = ((by + dy) * 3 + (bx + dx)) * 12;
    }

#pragma unroll
    for (int it = 0; it < 4; ++it) {
        const int ly = by * 32 + it * 8 + rr;   // tile-local y
        const int y  = tileY * 64 + ly;
        const float wy = ((float)ly + 0.5f) * 0.015625f + (0.5f - (float)by);
        const float v1 = wy, v0 = 1.0f - wy;

        const int gofs = (b * 1024 + y) * 1024 + tileX * 64 + lx;
        const int fofs = ((b * 3) * 1024 + y) * 1024 + tileX * 64 + lx;

        const float4 gv  = *reinterpret_cast<const float4*>(guide + gofs);
        const float4 f0v = *reinterpret_cast<const float4*>(fr + fofs);
        const float4 f1v = *reinterpret_cast<const float4*>(fr + fofs + 1048576);
        const float4 f2v = *reinterpret_cast<const float4*>(fr + fofs + 2097152);

        const float gva[4] = {gv.x, gv.y, gv.z, gv.w};
        const float fa0[4] = {f0v.x, f0v.y, f0v.z, f0v.w};
        const float fa1[4] = {f1v.x, f1v.y, f1v.z, f1v.w};
        const float fa2[4] = {f2v.x, f2v.y, f2v.z, f2v.w};

        float o0a[4], o1a[4], o2a[4];

#pragma unroll
        for (int p = 0; p < 4; ++p) {
            const float g  = gva[p];
            const float gz = g * 8.0f - 0.5f;
            int s = (int)floorf(gz);
            s = min(max(s, 0), 7);
            const float wz = fmaxf(gz - (float)s, 0.0f);
            const float zl = 1.0f - wz, zh = wz;
            const int sbase = s * ZSTRIDE;

            float acc[12];
#pragma unroll
            for (int c = 0; c < 12; ++c) acc[c] = 0.0f;

#pragma unroll
            for (int k = 0; k < 4; ++k) {
                const float wgt = ((k >> 1) ? v1 : v0) * ((k & 1) ? u1[p] : u0[p]);
                const float wl = wgt * zl;
                const float wh = wgt * zh;
                const unsigned int* cp = &lds[sbase + cofs[k]];
#pragma unroll
                for (int q = 0; q < 3; ++q) {
                    const uint4 dq = *reinterpret_cast<const uint4*>(cp + q * 4);
                    const unsigned int dw[4] = {dq.x, dq.y, dq.z, dq.w};
#pragma unroll
                    for (int kk = 0; kk < 4; ++kk) {
                        const int c = q * 4 + kk;
                        acc[c] = fmaf(wl, bf_lo(dw[kk]), acc[c]);
                        acc[c] = fmaf(wh, bf_hi(dw[kk]), acc[c]);
                    }
                }
            }

            const float f0 = fa0[p], f1 = fa1[p], f2 = fa2[p];
            o0a[p] = fmaf(acc[0], f0, fmaf(acc[1], f1, fmaf(acc[2],  f2, acc[3])));
            o1a[p] = fmaf(acc[4], f0, fmaf(acc[5], f1, fmaf(acc[6],  f2, acc[7])));
            o2a[p] = fmaf(acc[8], f0, fmaf(acc[9], f1, fmaf(acc[10], f2, acc[11])));
        }

        const float4 O0 = {o0a[0], o0a[1], o0a[2], o0a[3]};
        const float4 O1 = {o1a[0], o1a[1], o1a[2], o1a[3]};
        const float4 O2 = {o2a[0], o2a[1], o2a[2], o2a[3]};
        *reinterpret_cast<float4*>(out + fofs)           = O0;
        *reinterpret_cast<float4*>(out + fofs + 1048576) = O1;
        *reinterpret_cast<float4*>(out + fofs + 2097152) = O2;
    }
}

extern "C" void kernel_launch(void* const* d_in, const int* in_sizes, int n_in,
                              void* d_out, int out_size, void* d_ws, size_t ws_size,
                              hipStream_t stream) {
    const float* grid  = (const float*)d_in[0];
    const float* guide = (const float*)d_in[1];
    const float* fr    = (const float*)d_in[2];
    float* out = (float*)d_out;

    dim3 g(256, 4);   // 16x16 tiles of 64x64 px, 4 batches
    dim3 blk(256);
    hipLaunchKernelGGL(slice_apply, g, blk, 0, stream, grid, guide, fr, out);
}